// Round 7
// baseline (385.868 us; speedup 1.0000x reference)
//
#include <hip/hip_runtime.h>
#include <hip/hip_bf16.h>

typedef __bf16 bf16;
typedef __bf16 bf16x8 __attribute__((ext_vector_type(8)));
typedef float  floatx4 __attribute__((ext_vector_type(4)));

#define EPSF    1e-7f
#define MAXNORM 0.99999f   // (1 - 1e-5) / sqrt(C), C = 1
#define TS_LD   136        // padded leading dim for LDS intermediate tile

// rowwise scale implementing logmap0(proj(expmap0(h))) = scale(||h||) * h
__device__ __forceinline__ float hyp_scale(float ss) {
    float n  = sqrtf(ss);
    float nh = fmaxf(n, EPSF);
    float s1 = tanhf(nh) / nh;
    float nx = s1 * n;
    if (nx > MAXNORM) { s1 *= MAXNORM / nx; nx = MAXNORM; }
    float nx2 = fmaxf(nx, EPSF);
    return (atanhf(nx2) / nx2) * s1;
}

__device__ __forceinline__ bf16x8 cvt8(float4 a, float4 b) {
    bf16x8 r;
    r[0] = (bf16)a.x; r[1] = (bf16)a.y; r[2] = (bf16)a.z; r[3] = (bf16)a.w;
    r[4] = (bf16)b.x; r[5] = (bf16)b.y; r[6] = (bf16)b.z; r[7] = (bf16)b.w;
    return r;
}

// XOR-granule swizzle for a [128][128] bf16 LDS tile (16B granules)
__device__ __forceinline__ int sw128(int row, int k) {
    return row * 128 + (((k >> 3) ^ (row & 15)) << 3) + (k & 7);
}

// ---------------------------------------------------------------------------
// K1: embed + msg0 fused.  Per block: 128 rows.
//   h = X@Wemb^T ; t0 = rowscale(h) ; m0 = t0@Wmsg0 + b  -> M (rows), MT ([b][dim][node])
// ---------------------------------------------------------------------------
__global__ __launch_bounds__(256) void embed_msg(
    const float* __restrict__ X, const float* __restrict__ Wemb,
    const float* __restrict__ Wmsg, const float* __restrict__ bmsg,
    bf16* __restrict__ M, bf16* __restrict__ MT)
{
    __shared__ __align__(16) bf16 Xs[128 * 128];
    __shared__ __align__(16) bf16 Ws[128 * 128];
    __shared__ __align__(16) bf16 W2[128 * 128];
    __shared__ __align__(16) bf16 Ts[128 * TS_LD];
    const int tid = threadIdx.x, bx = blockIdx.x;

    // stage X fp32->bf16 (2048 granules)
    {
        const float4* Xg = reinterpret_cast<const float4*>(X + (size_t)bx * 16384);
        #pragma unroll
        for (int i = 0; i < 8; ++i) {
            int g = tid + i * 256, row = g >> 4, gc = g & 15;
            float4 v0 = Xg[2 * g], v1 = Xg[2 * g + 1];
            *reinterpret_cast<bf16x8*>(&Xs[row * 128 + ((gc ^ (row & 15)) << 3)]) = cvt8(v0, v1);
        }
    }
    // stage Wemb [out][in] direct -> Ws[n][k]
    {
        const float4* Wg = reinterpret_cast<const float4*>(Wemb);
        #pragma unroll
        for (int i = 0; i < 8; ++i) {
            int g = tid + i * 256, row = g >> 4, gc = g & 15;
            float4 v0 = Wg[2 * g], v1 = Wg[2 * g + 1];
            *reinterpret_cast<bf16x8*>(&Ws[row * 128 + ((gc ^ (row & 15)) << 3)]) = cvt8(v0, v1);
        }
    }
    // stage Wmsg [in][out] transposed -> W2[n][k]
    {
        const int c0 = (tid & 15) * 8;
        #pragma unroll
        for (int rr = 0; rr < 8; ++rr) {
            int r = (tid >> 4) * 8 + rr;
            const float4* p = reinterpret_cast<const float4*>(Wmsg + r * 128 + c0);
            float4 v0 = p[0], v1 = p[1];
            float vv[8] = {v0.x, v0.y, v0.z, v0.w, v1.x, v1.y, v1.z, v1.w};
            #pragma unroll
            for (int j = 0; j < 8; ++j) {
                int n = c0 + j;
                W2[n * 128 + (((r >> 3) ^ (n & 15)) << 3) + (r & 7)] = (bf16)vv[j];
            }
        }
    }
    __syncthreads();

    const int lane = tid & 63, wv = tid >> 6, n16 = lane & 15, quad = lane >> 4;
    const int rbase = wv * 32;

    // phase 1: h = X @ Wemb^T
    floatx4 acc[2][8];
    #pragma unroll
    for (int a = 0; a < 2; ++a)
        #pragma unroll
        for (int c = 0; c < 8; ++c) acc[a][c] = (floatx4){0.f, 0.f, 0.f, 0.f};
    #pragma unroll
    for (int kc = 0; kc < 4; ++kc) {
        int k0 = kc * 32 + quad * 8;
        bf16x8 a0 = *reinterpret_cast<const bf16x8*>(&Xs[sw128(rbase + n16, k0)]);
        bf16x8 a1 = *reinterpret_cast<const bf16x8*>(&Xs[sw128(rbase + 16 + n16, k0)]);
        #pragma unroll
        for (int ct = 0; ct < 8; ++ct) {
            bf16x8 b = *reinterpret_cast<const bf16x8*>(&Ws[sw128(ct * 16 + n16, k0)]);
            acc[0][ct] = __builtin_amdgcn_mfma_f32_16x16x32_bf16(a0, b, acc[0][ct], 0, 0, 0);
            acc[1][ct] = __builtin_amdgcn_mfma_f32_16x16x32_bf16(a1, b, acc[1][ct], 0, 0, 0);
        }
    }
    // rowscale -> t0 into Ts (padded)
    #pragma unroll
    for (int rt = 0; rt < 2; ++rt) {
        #pragma unroll
        for (int r = 0; r < 4; ++r) {
            int row = rbase + rt * 16 + quad * 4 + r;
            float u[8], ss = 0.f;
            #pragma unroll
            for (int ct = 0; ct < 8; ++ct) { u[ct] = acc[rt][ct][r]; ss += u[ct] * u[ct]; }
            #pragma unroll
            for (int off = 1; off < 16; off <<= 1) ss += __shfl_xor(ss, off);
            float sc = hyp_scale(ss);
            #pragma unroll
            for (int ct = 0; ct < 8; ++ct)
                Ts[row * TS_LD + ct * 16 + n16] = (bf16)(u[ct] * sc);
        }
    }
    __syncthreads();

    // phase 2: m0 = t0 @ Wmsg + b
    floatx4 acc2[2][8];
    #pragma unroll
    for (int a = 0; a < 2; ++a)
        #pragma unroll
        for (int c = 0; c < 8; ++c) acc2[a][c] = (floatx4){0.f, 0.f, 0.f, 0.f};
    #pragma unroll
    for (int kc = 0; kc < 4; ++kc) {
        int k0 = kc * 32 + quad * 8;
        bf16x8 a0 = *reinterpret_cast<const bf16x8*>(&Ts[(rbase + n16) * TS_LD + k0]);
        bf16x8 a1 = *reinterpret_cast<const bf16x8*>(&Ts[(rbase + 16 + n16) * TS_LD + k0]);
        #pragma unroll
        for (int ct = 0; ct < 8; ++ct) {
            bf16x8 b = *reinterpret_cast<const bf16x8*>(&W2[sw128(ct * 16 + n16, k0)]);
            acc2[0][ct] = __builtin_amdgcn_mfma_f32_16x16x32_bf16(a0, b, acc2[0][ct], 0, 0, 0);
            acc2[1][ct] = __builtin_amdgcn_mfma_f32_16x16x32_bf16(a1, b, acc2[1][ct], 0, 0, 0);
        }
    }
    float bv[8];
    #pragma unroll
    for (int ct = 0; ct < 8; ++ct) bv[ct] = bmsg[ct * 16 + n16];
    #pragma unroll
    for (int rt = 0; rt < 2; ++rt) {
        #pragma unroll
        for (int r = 0; r < 4; ++r) {
            int lrow = rbase + rt * 16 + quad * 4 + r;
            size_t grow = (size_t)bx * 128 + lrow;
            #pragma unroll
            for (int ct = 0; ct < 8; ++ct) {
                bf16 o = (bf16)(acc2[rt][ct][r] + bv[ct]);
                M[grow * 128 + ct * 16 + n16] = o;
                MT[((grow >> 10) * 128 + ct * 16 + n16) * 1024 + (grow & 1023)] = o;
            }
        }
    }
}

// ---------------------------------------------------------------------------
// K2/K3: adjmm + aggW + relu + rowscale + (msg | proj) fused.
// BARRIER-FREE K-loop: Adj has zero reuse (each element feeds exactly one
// wave's fragment) and mT is k-contiguous in memory, so both MFMA operands
// stream DIRECTLY from global into fragments. No LDS staging, no
// __syncthreads in the K-loop -> loads pipeline freely (vmcnt(N) style).
// Wave = 16 rows x 128 dims. One barrier total (weight staging).
// ---------------------------------------------------------------------------
template <int LAST>
__global__ __launch_bounds__(512) void adj_fused(
    const float* __restrict__ Adj, const bf16* __restrict__ MT,
    const bf16* __restrict__ Mprev,
    const float* __restrict__ Wagg, const float* __restrict__ bagg,
    const float* __restrict__ W2f,  const float* __restrict__ b2,
    const float* __restrict__ Mask,
    bf16* __restrict__ Mout, bf16* __restrict__ MTout, float* __restrict__ Out)
{
    __shared__ __align__(16) bf16 Ts[128 * TS_LD];   // 34 KB
    __shared__ __align__(16) bf16 Wa[128 * 128];     // 32 KB
    __shared__ __align__(16) bf16 W2[128 * 128];     // 32 KB

    const int tid = threadIdx.x, bid = blockIdx.x;
    const int mt = bid >> 5, b = bid & 31;
    const float* Ag = Adj + ((size_t)b << 20) + ((size_t)mt << 17);
    const bf16*  Bg = MT  + ((size_t)b << 17);

    const int lane = tid & 63, wv = tid >> 6, n16 = lane & 15, quad = lane >> 4;

    // ---- stage Wagg [in][out] transposed -> Wa[n][k] (512 threads) ----
    {
        const int c0 = (tid & 15) * 8;
        #pragma unroll
        for (int rr = 0; rr < 4; ++rr) {
            int r = (tid >> 4) * 4 + rr;
            const float4* p = reinterpret_cast<const float4*>(Wagg + r * 128 + c0);
            float4 v0 = p[0], v1 = p[1];
            float vv[8] = {v0.x, v0.y, v0.z, v0.w, v1.x, v1.y, v1.z, v1.w};
            #pragma unroll
            for (int j = 0; j < 8; ++j) {
                int n = c0 + j;
                Wa[n * 128 + (((r >> 3) ^ (n & 15)) << 3) + (r & 7)] = (bf16)vv[j];
            }
        }
    }
    // ---- stage W2: LAST? [out][in] direct : [in][out] transposed ----
    if (LAST) {
        const float4* Wg = reinterpret_cast<const float4*>(W2f);
        #pragma unroll
        for (int i = 0; i < 4; ++i) {
            int g = tid + i * 512, row = g >> 4, gc = g & 15;
            float4 v0 = Wg[2 * g], v1 = Wg[2 * g + 1];
            *reinterpret_cast<bf16x8*>(&W2[row * 128 + ((gc ^ (row & 15)) << 3)]) = cvt8(v0, v1);
        }
    } else {
        const int c0 = (tid & 15) * 8;
        #pragma unroll
        for (int rr = 0; rr < 4; ++rr) {
            int r = (tid >> 4) * 4 + rr;
            const float4* p = reinterpret_cast<const float4*>(W2f + r * 128 + c0);
            float4 v0 = p[0], v1 = p[1];
            float vv[8] = {v0.x, v0.y, v0.z, v0.w, v1.x, v1.y, v1.z, v1.w};
            #pragma unroll
            for (int j = 0; j < 8; ++j) {
                int n = c0 + j;
                W2[n * 128 + (((r >> 3) ^ (n & 15)) << 3) + (r & 7)] = (bf16)vv[j];
            }
        }
    }

    // ---- barrier-free K-loop: direct-fragment streaming ----
    const int rowA = wv * 16 + n16;                    // this lane's A row (disjoint per wave)
    const float* Arow = Ag + (size_t)rowA * 1024;
    const bf16*  Brow = Bg + (size_t)n16 * 1024;       // + ct*16*1024 per ct
    const int s = (bid * 5) & 31;                      // per-block K-phase stagger

    floatx4 acc[8];
    #pragma unroll
    for (int c = 0; c < 8; ++c) acc[c] = (floatx4){0.f, 0.f, 0.f, 0.f};

    #pragma unroll 4
    for (int it = 0; it < 32; ++it) {
        const int kc = (it + s) & 31;
        const int k0 = kc * 32 + quad * 8;
        float4 a0 = *reinterpret_cast<const float4*>(Arow + k0);
        float4 a1 = *reinterpret_cast<const float4*>(Arow + k0 + 4);
        bf16x8 af = cvt8(a0, a1);
        #pragma unroll
        for (int ct = 0; ct < 8; ++ct) {
            bf16x8 bf = *reinterpret_cast<const bf16x8*>(Brow + (size_t)(ct * 16) * 1024 + k0);
            acc[ct] = __builtin_amdgcn_mfma_f32_16x16x32_bf16(af, bf, acc[ct], 0, 0, 0);
        }
    }

    // ---- write agg C-tiles into padded Ts (wave-local rows) ----
    const int rbase = wv * 16;
    #pragma unroll
    for (int ct = 0; ct < 8; ++ct)
        #pragma unroll
        for (int r = 0; r < 4; ++r)
            Ts[(rbase + quad * 4 + r) * TS_LD + ct * 16 + n16] = (bf16)acc[ct][r];

    __syncthreads();   // Wa/W2 staging visible (Ts rows are wave-local)

    // ---- phase 3: u = relu(agg@Wagg + bagg + m_prev); t = rowscale(u) -> Ts ----
    const size_t growbase = (size_t)b * 1024 + (size_t)mt * 128;
    floatx4 acc2[8];
    #pragma unroll
    for (int c = 0; c < 8; ++c) acc2[c] = (floatx4){0.f, 0.f, 0.f, 0.f};
    #pragma unroll
    for (int kc = 0; kc < 4; ++kc) {
        int k0 = kc * 32 + quad * 8;
        bf16x8 a = *reinterpret_cast<const bf16x8*>(&Ts[(rbase + n16) * TS_LD + k0]);
        #pragma unroll
        for (int ct = 0; ct < 8; ++ct) {
            bf16x8 bb = *reinterpret_cast<const bf16x8*>(&Wa[sw128(ct * 16 + n16, k0)]);
            acc2[ct] = __builtin_amdgcn_mfma_f32_16x16x32_bf16(a, bb, acc2[ct], 0, 0, 0);
        }
    }
    {
        float bva[8];
        #pragma unroll
        for (int ct = 0; ct < 8; ++ct) bva[ct] = bagg[ct * 16 + n16];
        #pragma unroll
        for (int r = 0; r < 4; ++r) {
            int row = rbase + quad * 4 + r;
            size_t grow = growbase + row;
            float u[8], ss = 0.f;
            #pragma unroll
            for (int ct = 0; ct < 8; ++ct) {
                u[ct] = fmaxf(acc2[ct][r] + bva[ct] + (float)Mprev[grow * 128 + ct * 16 + n16], 0.f);
                ss += u[ct] * u[ct];
            }
            #pragma unroll
            for (int off = 1; off < 16; off <<= 1) ss += __shfl_xor(ss, off);
            float sc = hyp_scale(ss);
            #pragma unroll
            for (int ct = 0; ct < 8; ++ct)
                Ts[row * TS_LD + ct * 16 + n16] = (bf16)(u[ct] * sc);
        }
    }
    // same-wave rows only: per-wave DS ordering makes a barrier unnecessary here

    // ---- phase 4: t @ W2 (+b2); LAST: *mask -> fp32 Out; else -> Mout/MTout ----
    floatx4 acc3[8];
    #pragma unroll
    for (int c = 0; c < 8; ++c) acc3[c] = (floatx4){0.f, 0.f, 0.f, 0.f};
    #pragma unroll
    for (int kc = 0; kc < 4; ++kc) {
        int k0 = kc * 32 + quad * 8;
        bf16x8 a = *reinterpret_cast<const bf16x8*>(&Ts[(rbase + n16) * TS_LD + k0]);
        #pragma unroll
        for (int ct = 0; ct < 8; ++ct) {
            bf16x8 bb = *reinterpret_cast<const bf16x8*>(&W2[sw128(ct * 16 + n16, k0)]);
            acc3[ct] = __builtin_amdgcn_mfma_f32_16x16x32_bf16(a, bb, acc3[ct], 0, 0, 0);
        }
    }
    float bv2[8];
    #pragma unroll
    for (int ct = 0; ct < 8; ++ct) bv2[ct] = b2[ct * 16 + n16];
    #pragma unroll
    for (int r = 0; r < 4; ++r) {
        int row = rbase + quad * 4 + r;
        size_t grow = growbase + row;
        if (LAST) {
            float mk = Mask[grow];
            #pragma unroll
            for (int ct = 0; ct < 8; ++ct)
                Out[grow * 128 + ct * 16 + n16] = (acc3[ct][r] + bv2[ct]) * mk;
        } else {
            #pragma unroll
            for (int ct = 0; ct < 8; ++ct) {
                bf16 o = (bf16)(acc3[ct][r] + bv2[ct]);
                Mout[grow * 128 + ct * 16 + n16] = o;
                MTout[((grow >> 10) * 128 + ct * 16 + n16) * 1024 + (grow & 1023)] = o;
            }
        }
    }
}

extern "C" void kernel_launch(void* const* d_in, const int* in_sizes, int n_in,
                              void* d_out, int out_size, void* d_ws, size_t ws_size,
                              hipStream_t stream)
{
    const float* X    = (const float*)d_in[0];   // [32,1024,128]
    const float* Adj  = (const float*)d_in[1];   // [32,1024,1024]
    const float* Mask = (const float*)d_in[2];   // [32,1024,1]
    const float* Wemb = (const float*)d_in[3];   // [128,128] (out,in)
    const float* Wmsg = (const float*)d_in[4];   // [2,128,128] (in,out)
    const float* bmsg = (const float*)d_in[5];   // [2,128]
    const float* Wagg = (const float*)d_in[6];   // [2,128,128] (in,out)
    const float* bagg = (const float*)d_in[7];   // [2,128]
    const float* Wprj = (const float*)d_in[8];   // [128,128] (out,in)
    const float* bprj = (const float*)d_in[9];   // [128]
    float* out = (float*)d_out;

    const size_t BN = 32768;
    bf16* m0  = (bf16*)d_ws;         // [BN,128]
    bf16* m0T = m0  + BN * 128;      // [32,128,1024]
    bf16* m1  = m0T + BN * 128;      // [BN,128]
    bf16* m1T = m1  + BN * 128;      // [32,128,1024]

    embed_msg<<<256, 256, 0, stream>>>(X, Wemb, Wmsg, bmsg, m0, m0T);
    adj_fused<0><<<256, 512, 0, stream>>>(Adj, m0T, m0, Wagg, bagg,
                                          Wmsg + 16384, bmsg + 128, nullptr,
                                          m1, m1T, nullptr);
    adj_fused<1><<<256, 512, 0, stream>>>(Adj, m1T, m1, Wagg + 16384, bagg + 128,
                                          Wprj, bprj, Mask,
                                          nullptr, nullptr, out);
}